// Round 1
// baseline (7145.493 us; speedup 1.0000x reference)
//
#include <hip/hip_runtime.h>

#define TT 512
#define HH 64
#define GATES 256   // 4*H
#define BB 16       // batch rows per block

__device__ __forceinline__ float sigm(float x)      { return 1.f / (1.f + __expf(-x)); }
__device__ __forceinline__ float tanh_fast(float x) { return 1.f - 2.f / (__expf(2.f * x) + 1.f); }

__device__ __forceinline__ void fma4(float4& a, float s, const float4 w) {
    a.x = fmaf(s, w.x, a.x);
    a.y = fmaf(s, w.y, a.y);
    a.z = fmaf(s, w.z, a.z);
    a.w = fmaf(s, w.w, a.w);
}

// LDS layout (floats):
//   sW0 [68][256]  k-major: rows 0..63 = w_hh0^T, rows 64..67 = w_ih0^T   (69632 B)
//   sW2 [64][256]  k-major: w_hh1^T                                       (65536 B)
//   sG  [16][256]  gate pre-activations                                   (16384 B)
//   sH1 [16][68]   cols 0..63 = h1, cols 64..67 = x_t                     ( 4352 B)
//   sH2 [16][64]   h2                                                     ( 4096 B)
// total = 160000 B  (needs dynamic-LDS opt-in > 64 KB)

__global__ __launch_bounds__(256) void lstm_fused(
    const float* __restrict__ x,
    const float* __restrict__ w_ih0, const float* __restrict__ w_hh0,
    const float* __restrict__ b_ih0, const float* __restrict__ b_hh0,
    const float* __restrict__ w_ih1, const float* __restrict__ w_hh1,
    const float* __restrict__ b_ih1, const float* __restrict__ b_hh1,
    const float* __restrict__ fc1_w, const float* __restrict__ fc1_b,
    const float* __restrict__ fc2_w, const float* __restrict__ fc2_b,
    float* __restrict__ out)
{
    extern __shared__ float sm[];
    float* sW0 = sm;                  // [68][256]
    float* sW2 = sW0 + 68 * 256;      // [64][256]
    float* sG  = sW2 + 64 * 256;      // [16][256]
    float* sH1 = sG  + 16 * 256;      // [16][68]
    float* sH2 = sH1 + 16 * 68;       // [16][64]

    const int tid = threadIdx.x;
    const int gg  = tid & 63;         // gate group: gates 4*gg .. 4*gg+3
    const int rg  = tid >> 6;         // wave id: rows 4*rg .. 4*rg+3
    const int b0  = blockIdx.x * BB;

    // ---- prologue: stage weights k-major into LDS (one-time; write conflicts OK)
    for (int idx = tid; idx < 256 * 64; idx += 256) {
        int g = idx >> 6, k = idx & 63;
        sW0[k * 256 + g] = w_hh0[idx];
        sW2[k * 256 + g] = w_hh1[idx];
    }
    for (int idx = tid; idx < 256 * 4; idx += 256) {
        int g = idx >> 2, i = idx & 3;
        sW0[(64 + i) * 256 + g] = w_ih0[idx];
    }
    for (int idx = tid; idx < 16 * 68; idx += 256) sH1[idx] = 0.f;
    for (int idx = tid; idx < 16 * 64; idx += 256) sH2[idx] = 0.f;

    float4 bias0, bias1;
    bias0.x = b_ih0[4 * gg + 0] + b_hh0[4 * gg + 0];
    bias0.y = b_ih0[4 * gg + 1] + b_hh0[4 * gg + 1];
    bias0.z = b_ih0[4 * gg + 2] + b_hh0[4 * gg + 2];
    bias0.w = b_ih0[4 * gg + 3] + b_hh0[4 * gg + 3];
    bias1.x = b_ih1[4 * gg + 0] + b_hh1[4 * gg + 0];
    bias1.y = b_ih1[4 * gg + 1] + b_hh1[4 * gg + 1];
    bias1.z = b_ih1[4 * gg + 2] + b_hh1[4 * gg + 2];
    bias1.w = b_ih1[4 * gg + 3] + b_hh1[4 * gg + 3];

    float c1[4] = {0.f, 0.f, 0.f, 0.f};
    float c2[4] = {0.f, 0.f, 0.f, 0.f};

    // x for t=0
    if (tid < BB) {
        float4 xv = ((const float4*)x)[(size_t)(b0 + tid) * TT + 0];
        *(float4*)(sH1 + tid * 68 + 64) = xv;
    }
    __syncthreads();

    const int jEW = tid & 63;            // elementwise: j index
    const int rEW = (tid >> 6) * 4;      // elementwise: row base

    for (int t = 0; t < TT; ++t) {
        // ================= layer-1 GEMM: gates1 = bias0 + [h1 | x_t] @ W0 (K=68)
        float4 acc[4];
        #pragma unroll
        for (int r = 0; r < 4; ++r) acc[r] = bias0;
        {
            const float4* W = (const float4*)sW0;
            const float4* Hrow = (const float4*)sH1;
            #pragma unroll 4
            for (int kc = 0; kc < 17; ++kc) {
                float4 w0 = W[(4 * kc + 0) * 64 + gg];
                float4 w1 = W[(4 * kc + 1) * 64 + gg];
                float4 w2 = W[(4 * kc + 2) * 64 + gg];
                float4 w3 = W[(4 * kc + 3) * 64 + gg];
                #pragma unroll
                for (int r = 0; r < 4; ++r) {
                    float4 hv = Hrow[(rg * 4 + r) * 17 + kc];   // wave-uniform broadcast
                    fma4(acc[r], hv.x, w0);
                    fma4(acc[r], hv.y, w1);
                    fma4(acc[r], hv.z, w2);
                    fma4(acc[r], hv.w, w3);
                }
            }
        }
        #pragma unroll
        for (int r = 0; r < 4; ++r)
            ((float4*)sG)[(rg * 4 + r) * 64 + gg] = acc[r];
        __syncthreads();

        // ================= elementwise layer 1
        #pragma unroll
        for (int rr = 0; rr < 4; ++rr) {
            int r = rEW + rr;
            float iv = sG[r * 256 +       jEW];
            float fv = sG[r * 256 +  64 + jEW];
            float gv = sG[r * 256 + 128 + jEW];
            float ov = sG[r * 256 + 192 + jEW];
            c1[rr] = sigm(fv) * c1[rr] + sigm(iv) * tanh_fast(gv);
            sH1[r * 68 + jEW] = sigm(ov) * tanh_fast(c1[rr]);
        }
        __syncthreads();

        // ================= layer-2 GEMM: gates2 = bias1 + h1new @ w_ih1^T + h2 @ W2
        #pragma unroll
        for (int r = 0; r < 4; ++r) acc[r] = bias1;
        {
            // part a: w_ih1 streamed from global (g-major, L2-hot)
            const float4* Hrow = (const float4*)sH1;
            #pragma unroll 4
            for (int kc = 0; kc < 16; ++kc) {
                float4 wg0 = *(const float4*)(w_ih1 + (4 * gg + 0) * 64 + 4 * kc);
                float4 wg1 = *(const float4*)(w_ih1 + (4 * gg + 1) * 64 + 4 * kc);
                float4 wg2 = *(const float4*)(w_ih1 + (4 * gg + 2) * 64 + 4 * kc);
                float4 wg3 = *(const float4*)(w_ih1 + (4 * gg + 3) * 64 + 4 * kc);
                #pragma unroll
                for (int r = 0; r < 4; ++r) {
                    float4 hv = Hrow[(rg * 4 + r) * 17 + kc];
                    acc[r].x = fmaf(hv.x, wg0.x, fmaf(hv.y, wg0.y, fmaf(hv.z, wg0.z, fmaf(hv.w, wg0.w, acc[r].x))));
                    acc[r].y = fmaf(hv.x, wg1.x, fmaf(hv.y, wg1.y, fmaf(hv.z, wg1.z, fmaf(hv.w, wg1.w, acc[r].y))));
                    acc[r].z = fmaf(hv.x, wg2.x, fmaf(hv.y, wg2.y, fmaf(hv.z, wg2.z, fmaf(hv.w, wg2.w, acc[r].z))));
                    acc[r].w = fmaf(hv.x, wg3.x, fmaf(hv.y, wg3.y, fmaf(hv.z, wg3.z, fmaf(hv.w, wg3.w, acc[r].w))));
                }
            }
            // part b: w_hh1 from LDS, h2 from LDS
            const float4* W = (const float4*)sW2;
            const float4* H2row = (const float4*)sH2;
            #pragma unroll 4
            for (int kc = 0; kc < 16; ++kc) {
                float4 w0 = W[(4 * kc + 0) * 64 + gg];
                float4 w1 = W[(4 * kc + 1) * 64 + gg];
                float4 w2 = W[(4 * kc + 2) * 64 + gg];
                float4 w3 = W[(4 * kc + 3) * 64 + gg];
                #pragma unroll
                for (int r = 0; r < 4; ++r) {
                    float4 hv = H2row[(rg * 4 + r) * 16 + kc];
                    fma4(acc[r], hv.x, w0);
                    fma4(acc[r], hv.y, w1);
                    fma4(acc[r], hv.z, w2);
                    fma4(acc[r], hv.w, w3);
                }
            }
        }
        #pragma unroll
        for (int r = 0; r < 4; ++r)
            ((float4*)sG)[(rg * 4 + r) * 64 + gg] = acc[r];
        __syncthreads();

        // ================= elementwise layer 2 (+ prefetch x for t+1)
        #pragma unroll
        for (int rr = 0; rr < 4; ++rr) {
            int r = rEW + rr;
            float iv = sG[r * 256 +       jEW];
            float fv = sG[r * 256 +  64 + jEW];
            float gv = sG[r * 256 + 128 + jEW];
            float ov = sG[r * 256 + 192 + jEW];
            c2[rr] = sigm(fv) * c2[rr] + sigm(iv) * tanh_fast(gv);
            sH2[r * 64 + jEW] = sigm(ov) * tanh_fast(c2[rr]);
        }
        if (t + 1 < TT && tid < BB) {
            float4 xv = ((const float4*)x)[(size_t)(b0 + tid) * TT + (t + 1)];
            *(float4*)(sH1 + tid * 68 + 64) = xv;   // cols 64..67 only; no reader until next barrier
        }
        __syncthreads();
    }

    // ================= FC head: y = relu(h2_last @ fc1^T + b1); out = relu(y @ fc2^T + b2)
    for (int idx = tid; idx < 16 * 32; idx += 256) {
        int r = idx >> 5, m = idx & 31;
        float s = fc1_b[m];
        #pragma unroll 8
        for (int k = 0; k < 64; ++k) s = fmaf(sH2[r * 64 + k], fc1_w[m * 64 + k], s);
        sG[r * 32 + m] = fmaxf(s, 0.f);
    }
    __syncthreads();
    for (int idx = tid; idx < 16 * 2; idx += 256) {
        int r = idx >> 1, o = idx & 1;
        float s = fc2_b[o];
        #pragma unroll 8
        for (int m = 0; m < 32; ++m) s = fmaf(sG[r * 32 + m], fc2_w[o * 32 + m], s);
        out[(size_t)(b0 + r) * 2 + o] = fmaxf(s, 0.f);
    }
}

extern "C" void kernel_launch(void* const* d_in, const int* in_sizes, int n_in,
                              void* d_out, int out_size, void* d_ws, size_t ws_size,
                              hipStream_t stream) {
    const float* x     = (const float*)d_in[0];
    const float* w_ih0 = (const float*)d_in[1];
    const float* w_hh0 = (const float*)d_in[2];
    const float* b_ih0 = (const float*)d_in[3];
    const float* b_hh0 = (const float*)d_in[4];
    const float* w_ih1 = (const float*)d_in[5];
    const float* w_hh1 = (const float*)d_in[6];
    const float* b_ih1 = (const float*)d_in[7];
    const float* b_hh1 = (const float*)d_in[8];
    const float* fc1_w = (const float*)d_in[9];
    const float* fc1_b = (const float*)d_in[10];
    const float* fc2_w = (const float*)d_in[11];
    const float* fc2_b = (const float*)d_in[12];
    float* out = (float*)d_out;

    const int nB   = in_sizes[0] / (TT * 4);   // 4096
    const int grid = nB / BB;                  // 256 blocks
    const int smem = 160000;                   // bytes, > 64 KB -> opt-in

    hipFuncSetAttribute(reinterpret_cast<const void*>(lstm_fused),
                        hipFuncAttributeMaxDynamicSharedMemorySize, smem);

    lstm_fused<<<grid, 256, smem, stream>>>(x, w_ih0, w_hh0, b_ih0, b_hh0,
                                            w_ih1, w_hh1, b_ih1, b_hh1,
                                            fc1_w, fc1_b, fc2_w, fc2_b, out);
}

// Round 2
// 1243.309 us; speedup vs baseline: 5.7472x; 5.7472x over previous
//
#include <hip/hip_runtime.h>

#define TT 512
#define GG 256
#define MM 16      // batch rows per block
#define NW 8       // waves per block (512 threads)

typedef __bf16 bf16_t;
typedef bf16_t bf16x8 __attribute__((ext_vector_type(8)));
typedef float  f32x4  __attribute__((ext_vector_type(4)));

#define MFMA(A, B, C) __builtin_amdgcn_mfma_f32_16x16x32_bf16((A), (B), (C), 0, 0, 0)

__device__ __forceinline__ float sigm(float x)  { return 1.f / (1.f + __expf(-x)); }
__device__ __forceinline__ float tanhr(float x) { float e = __expf(2.f * x); return 1.f - 2.f / (e + 1.f); }

// split fp32[8] -> bf16 hi + bf16 lo fragments
__device__ __forceinline__ void split8(const float* p, bf16x8& hi, bf16x8& lo) {
#pragma unroll
    for (int e = 0; e < 8; ++e) {
        float v = p[e];
        bf16_t h = (bf16_t)v;
        hi[e] = h;
        lo[e] = (bf16_t)(v - (float)h);
    }
}

// MFMA 16x16x32 bf16 layouts used (k-labeling consistent between A and B, so any
// k-permutation is harmless; only row/col lane maps must be right):
//   A[m][k]: lane l holds m = l%16, k = (l/16)*8 + e
//   B[k][n]: lane l holds n = l%16, k = (l/16)*8 + e
//   D[m][n]: lane l holds n = l%16, m = (l/16)*4 + q   (verified layout)
// Frag-linear LDS plane for A (per precision): elem addr = (kt*64 + chunk(l))*8 + e,
// chunk(l) = l ^ ((l>>4)&3)  — XOR spreads EW scatter-writes across banks.

__global__ __launch_bounds__(512, 2) void lstm_mfma(
    const float* __restrict__ x,
    const float* __restrict__ w_ih0, const float* __restrict__ w_hh0,
    const float* __restrict__ b_ih0, const float* __restrict__ b_hh0,
    const float* __restrict__ w_ih1, const float* __restrict__ w_hh1,
    const float* __restrict__ b_ih1, const float* __restrict__ b_hh1,
    const float* __restrict__ fc1_w, const float* __restrict__ fc1_b,
    const float* __restrict__ fc2_w, const float* __restrict__ fc2_b,
    float* __restrict__ out)
{
    __shared__ __align__(16) float sG[MM * 260];        // gate pre-activations, padded
    __shared__ __align__(16) unsigned h1hi[512], h1lo[512];  // 2 ktiles * 64 chunks * 4 u32
    __shared__ __align__(16) unsigned h2hi[512], h2lo[512];
    __shared__ __align__(16) float sH[MM * 68];         // last-step h2 (fp32) for FC
    __shared__ float sY[MM * 34];                       // fc1 output

    const int tid = threadIdx.x;
    const int l   = tid & 63;
    const int w   = tid >> 6;
    const int rbase = blockIdx.x * MM;

    const int lc = l & 15;                 // A-row / B-col / D-col lane index
    const int lq = l >> 4;                 // k-group / D-row group
    const int chunk = l ^ (lq & 3);        // swizzled frag chunk for this lane

    // ---------------- prologue: weights -> registers (B-fragments, hi/lo) ----------------
    bf16x8 w0h[2][2], w0l[2][2], w1h[2][2], w1l[2][2], w2h[2][2], w2l[2][2];
    float4 wx[2];
    float bs0[2], bs1[2];
#pragma unroll
    for (int nn = 0; nn < 2; ++nn) {
        const int g = (2 * w + nn) * 16 + lc;          // gate column owned by this lane
#pragma unroll
        for (int kt = 0; kt < 2; ++kt) {
            const int ko = kt * 32 + lq * 8;
            split8(w_hh0 + g * 64 + ko, w0h[nn][kt], w0l[nn][kt]);
            split8(w_ih1 + g * 64 + ko, w1h[nn][kt], w1l[nn][kt]);
            split8(w_hh1 + g * 64 + ko, w2h[nn][kt], w2l[nn][kt]);
        }
        wx[nn]  = *(const float4*)(w_ih0 + g * 4);
        bs0[nn] = b_ih0[g] + b_hh0[g];
        bs1[nn] = b_ih1[g] + b_hh1[g];
    }

    // zero h-state fragment planes (h0 = 0)
    h1hi[tid] = 0; h1lo[tid] = 0; h2hi[tid] = 0; h2lo[tid] = 0;

    // EW thread mapping: m = row, elements k = j and k = j+32 (ktile 0 / 1)
    const int m = tid >> 5;
    const int j = tid & 31;
    const int ea  = (j >> 3) * 16 + m;          // lane that consumes this element
    const int esz = ea ^ ((j >> 3) & 3);        // same chunk swizzle as reader
    const int eoff = esz * 8 + (j & 7);         // bf16-element offset within plane half
    float c1[2] = {0.f, 0.f}, c2[2] = {0.f, 0.f};

    // x prefetch bases: rows lq*4+q of this block
    const float4* xg = (const float4*)x;
    const size_t xb = (size_t)(rbase + lq * 4) * TT;
    float4 xv[4];
#pragma unroll
    for (int q = 0; q < 4; ++q) xv[q] = xg[xb + (size_t)q * TT + 0];

    __syncthreads();

    for (int t = 0; t < TT; ++t) {
        // prefetch next-step x (clamped dummy load at last step)
        const int tn = (t + 1 < TT) ? t + 1 : t;
        float4 xn[4];
#pragma unroll
        for (int q = 0; q < 4; ++q) xn[q] = xg[xb + (size_t)q * TT + tn];

        // ---------------- L1 GEMM: gates1 = bias0 + x*wih0 + h1 @ whh0^T ----------------
        bf16x8 ah[2], al[2];
#pragma unroll
        for (int kt = 0; kt < 2; ++kt) {
            ah[kt] = *(const bf16x8*)((const bf16_t*)h1hi + kt * 512 + chunk * 8);
            al[kt] = *(const bf16x8*)((const bf16_t*)h1lo + kt * 512 + chunk * 8);
        }
        f32x4 acc[2];
#pragma unroll
        for (int nn = 0; nn < 2; ++nn) {
#pragma unroll
            for (int q = 0; q < 4; ++q)
                acc[nn][q] = bs0[nn] + xv[q].x * wx[nn].x + xv[q].y * wx[nn].y
                           + xv[q].z * wx[nn].z + xv[q].w * wx[nn].w;
        }
#pragma unroll
        for (int nn = 0; nn < 2; ++nn) {
#pragma unroll
            for (int kt = 0; kt < 2; ++kt) {
                acc[nn] = MFMA(al[kt], w0h[nn][kt], acc[nn]);
                acc[nn] = MFMA(ah[kt], w0l[nn][kt], acc[nn]);
                acc[nn] = MFMA(ah[kt], w0h[nn][kt], acc[nn]);
            }
        }
#pragma unroll
        for (int nn = 0; nn < 2; ++nn) {
            const int col = (2 * w + nn) * 16 + lc;
#pragma unroll
            for (int q = 0; q < 4; ++q)
                sG[(lq * 4 + q) * 260 + col] = acc[nn][q];
        }
        __syncthreads();

        // ---------------- EW1: LSTM cell layer 1, write h1 frags ----------------
        {
            float hv[2];
#pragma unroll
            for (int u = 0; u < 2; ++u) {
                const int k = j + u * 32;
                float iv = sG[m * 260 + k];
                float fv = sG[m * 260 + 64 + k];
                float gv = sG[m * 260 + 128 + k];
                float ov = sG[m * 260 + 192 + k];
                float cn = sigm(fv) * c1[u] + sigm(iv) * tanhr(gv);
                c1[u] = cn;
                hv[u] = sigm(ov) * tanhr(cn);
            }
#pragma unroll
            for (int u = 0; u < 2; ++u) {
                bf16_t h  = (bf16_t)hv[u];
                bf16_t lo = (bf16_t)(hv[u] - (float)h);
                ((bf16_t*)h1hi)[u * 512 + eoff] = h;
                ((bf16_t*)h1lo)[u * 512 + eoff] = lo;
            }
        }
        __syncthreads();

        // ---------------- L2 GEMM: gates2 = bias1 + h1new @ wih1^T + h2 @ whh1^T ----------------
        bf16x8 p1h[2], p1l[2], p2h[2], p2l[2];
#pragma unroll
        for (int kt = 0; kt < 2; ++kt) {
            p1h[kt] = *(const bf16x8*)((const bf16_t*)h1hi + kt * 512 + chunk * 8);
            p1l[kt] = *(const bf16x8*)((const bf16_t*)h1lo + kt * 512 + chunk * 8);
            p2h[kt] = *(const bf16x8*)((const bf16_t*)h2hi + kt * 512 + chunk * 8);
            p2l[kt] = *(const bf16x8*)((const bf16_t*)h2lo + kt * 512 + chunk * 8);
        }
#pragma unroll
        for (int nn = 0; nn < 2; ++nn) {
#pragma unroll
            for (int q = 0; q < 4; ++q) acc[nn][q] = bs1[nn];
#pragma unroll
            for (int kt = 0; kt < 2; ++kt) {
                acc[nn] = MFMA(p1l[kt], w1h[nn][kt], acc[nn]);
                acc[nn] = MFMA(p1h[kt], w1l[nn][kt], acc[nn]);
                acc[nn] = MFMA(p1h[kt], w1h[nn][kt], acc[nn]);
                acc[nn] = MFMA(p2l[kt], w2h[nn][kt], acc[nn]);
                acc[nn] = MFMA(p2h[kt], w2l[nn][kt], acc[nn]);
                acc[nn] = MFMA(p2h[kt], w2h[nn][kt], acc[nn]);
            }
        }
#pragma unroll
        for (int nn = 0; nn < 2; ++nn) {
            const int col = (2 * w + nn) * 16 + lc;
#pragma unroll
            for (int q = 0; q < 4; ++q)
                sG[(lq * 4 + q) * 260 + col] = acc[nn][q];
        }
        __syncthreads();

        // ---------------- EW2: LSTM cell layer 2, write h2 frags ----------------
        {
            float hv[2];
#pragma unroll
            for (int u = 0; u < 2; ++u) {
                const int k = j + u * 32;
                float iv = sG[m * 260 + k];
                float fv = sG[m * 260 + 64 + k];
                float gv = sG[m * 260 + 128 + k];
                float ov = sG[m * 260 + 192 + k];
                float cn = sigm(fv) * c2[u] + sigm(iv) * tanhr(gv);
                c2[u] = cn;
                hv[u] = sigm(ov) * tanhr(cn);
            }
#pragma unroll
            for (int u = 0; u < 2; ++u) {
                bf16_t h  = (bf16_t)hv[u];
                bf16_t lo = (bf16_t)(hv[u] - (float)h);
                ((bf16_t*)h2hi)[u * 512 + eoff] = h;
                ((bf16_t*)h2lo)[u * 512 + eoff] = lo;
            }
            if (t == TT - 1) {
                sH[m * 68 + j]      = hv[0];
                sH[m * 68 + j + 32] = hv[1];
            }
        }
        __syncthreads();

#pragma unroll
        for (int q = 0; q < 4; ++q) xv[q] = xn[q];
    }

    // ---------------- FC head ----------------
    {
        const int r = tid >> 5, mo = tid & 31;
        float s = fc1_b[mo];
#pragma unroll 8
        for (int k = 0; k < 64; ++k) s = fmaf(sH[r * 68 + k], fc1_w[mo * 64 + k], s);
        sY[r * 34 + mo] = fmaxf(s, 0.f);
    }
    __syncthreads();
    if (tid < 32) {
        const int r = tid >> 1, o = tid & 1;
        float s = fc2_b[o];
#pragma unroll 8
        for (int mo = 0; mo < 32; ++mo) s = fmaf(sY[r * 34 + mo], fc2_w[o * 32 + mo], s);
        out[(size_t)(rbase + r) * 2 + o] = fmaxf(s, 0.f);
    }
}

extern "C" void kernel_launch(void* const* d_in, const int* in_sizes, int n_in,
                              void* d_out, int out_size, void* d_ws, size_t ws_size,
                              hipStream_t stream) {
    const float* x     = (const float*)d_in[0];
    const float* w_ih0 = (const float*)d_in[1];
    const float* w_hh0 = (const float*)d_in[2];
    const float* b_ih0 = (const float*)d_in[3];
    const float* b_hh0 = (const float*)d_in[4];
    const float* w_ih1 = (const float*)d_in[5];
    const float* w_hh1 = (const float*)d_in[6];
    const float* b_ih1 = (const float*)d_in[7];
    const float* b_hh1 = (const float*)d_in[8];
    const float* fc1_w = (const float*)d_in[9];
    const float* fc1_b = (const float*)d_in[10];
    const float* fc2_w = (const float*)d_in[11];
    const float* fc2_b = (const float*)d_in[12];
    float* out = (float*)d_out;

    const int nB   = in_sizes[0] / (TT * 4);   // 4096 rows
    const int grid = nB / MM;                  // 256 blocks

    lstm_mfma<<<grid, 512, 0, stream>>>(x, w_ih0, w_hh0, b_ih0, b_hh0,
                                        w_ih1, w_hh1, b_ih1, b_hh1,
                                        fc1_w, fc1_b, fc2_w, fc2_b, out);
}

// Round 3
// 1212.563 us; speedup vs baseline: 5.8929x; 1.0254x over previous
//
#include <hip/hip_runtime.h>

#define TT 512
#define MM 16      // batch rows per block

typedef __bf16 bf16_t;
typedef bf16_t bf16x8 __attribute__((ext_vector_type(8)));
typedef float  f32x4  __attribute__((ext_vector_type(4)));

#define MFMA(A, B, C) __builtin_amdgcn_mfma_f32_16x16x32_bf16((A), (B), (C), 0, 0, 0)

__device__ __forceinline__ float sigm(float x)  { return 1.f / (1.f + __expf(-x)); }
__device__ __forceinline__ float tanhr(float x) { float e = __expf(2.f * x); return 1.f - 2.f / (e + 1.f); }

// split fp32[8] -> bf16 hi + bf16 lo fragments
__device__ __forceinline__ void split8(const float* p, bf16x8& hi, bf16x8& lo) {
#pragma unroll
    for (int e = 0; e < 8; ++e) {
        float v = p[e];
        bf16_t h = (bf16_t)v;
        hi[e] = h;
        lo[e] = (bf16_t)(v - (float)h);
    }
}

// Build the x A-fragment: only k = 0..3 (lq==0, e<4) are valid, rest zero.
__device__ __forceinline__ void buildx(float4 xq, int lq, bf16x8& xh, bf16x8& xl) {
    float v[4] = {xq.x, xq.y, xq.z, xq.w};
#pragma unroll
    for (int e = 0; e < 8; ++e) {
        float vv = (e < 4 && lq == 0) ? v[e] : 0.f;
        bf16_t h = (bf16_t)vv;
        xh[e] = h;
        xl[e] = (bf16_t)(vv - (float)h);
    }
}

// MFMA 16x16x32 bf16 layouts (verified in R2):
//   A[m][k]: lane l holds m = l%16, k = (l/16)*8 + e
//   B[k][n]: lane l holds n = l%16, k = (l/16)*8 + e
//   D[m][n]: lane l holds n = l%16, m = (l/16)*4 + q
// Frag-linear LDS plane for A (per precision): bf16 addr = kt*512 + chunk(l)*8 + e,
// chunk(l) = l ^ (l>>4)  — XOR spreads EW scatter-writes across banks.

__global__ __launch_bounds__(512, 2) void lstm_pipe(
    const float* __restrict__ x,
    const float* __restrict__ w_ih0, const float* __restrict__ w_hh0,
    const float* __restrict__ b_ih0, const float* __restrict__ b_hh0,
    const float* __restrict__ w_ih1, const float* __restrict__ w_hh1,
    const float* __restrict__ b_ih1, const float* __restrict__ b_hh1,
    const float* __restrict__ fc1_w, const float* __restrict__ fc1_b,
    const float* __restrict__ fc2_w, const float* __restrict__ fc2_b,
    float* __restrict__ out)
{
    __shared__ __align__(16) float sG1[MM * 260];              // gates1(t+1)
    __shared__ __align__(16) float sG2[MM * 260];              // gates2(t)
    __shared__ __align__(16) unsigned h1hi[512], h1lo[512];    // h1 A-frag planes
    __shared__ __align__(16) unsigned h2hi[512], h2lo[512];    // h2 A-frag planes
    __shared__ __align__(16) float sH[MM * 68];                // last h2 for FC
    __shared__ float sY[MM * 34];

    const int tid = threadIdx.x;
    const int l   = tid & 63;
    const int w   = tid >> 6;
    const int rbase = blockIdx.x * MM;

    const int lc = l & 15;
    const int lq = l >> 4;
    const int chunk = l ^ lq;

    // ---------------- prologue: weights -> registers (B-fragments, hi/lo) ----------------
    bf16x8 w0h[2][2], w0l[2][2], w1h[2][2], w1l[2][2], w2h[2][2], w2l[2][2];
    bf16x8 wxh[2], wxl[2];
    float bs0[2], bs1[2];
#pragma unroll
    for (int nn = 0; nn < 2; ++nn) {
        const int g = (2 * w + nn) * 16 + lc;
#pragma unroll
        for (int kt = 0; kt < 2; ++kt) {
            const int ko = kt * 32 + lq * 8;
            split8(w_hh0 + g * 64 + ko, w0h[nn][kt], w0l[nn][kt]);
            split8(w_ih1 + g * 64 + ko, w1h[nn][kt], w1l[nn][kt]);
            split8(w_hh1 + g * 64 + ko, w2h[nn][kt], w2l[nn][kt]);
        }
        // x-weight B-frag: w_ih0[g][0..3] at k=0..3, zero elsewhere
        float4 w4 = *(const float4*)(w_ih0 + g * 4);
        buildx(w4, lq, wxh[nn], wxl[nn]);
        bs0[nn] = b_ih0[g] + b_hh0[g];
        bs1[nn] = b_ih1[g] + b_hh1[g];
    }

    h1hi[tid] = 0; h1lo[tid] = 0; h2hi[tid] = 0; h2lo[tid] = 0;

    // EW mapping: thread handles cells (m, j) and (m, j+32) of each layer
    const int m = tid >> 5;
    const int j = tid & 31;
    const int ea   = (j >> 3) * 16 + m;
    const int esz  = ea ^ ((j >> 3) & 3);
    const int eoff = esz * 8 + (j & 7);
    float c1[2] = {0.f, 0.f}, c2[2] = {0.f, 0.f};

    const float4* xg = (const float4*)x;
    const size_t xrow = (size_t)(rbase + lc) * TT;   // lanes 0-15 cover the 16 rows
    float4 xqA = xg[xrow + 0];                       // x(0) for prime
    float4 xq  = xg[xrow + 1];                       // x(t+1) at loop entry

    __syncthreads();

    // ---------------- prime: gates1(0) = bias0 + x(0) @ w_ih0^T  (h1(-1)=0) ----------------
    {
        bf16x8 xh, xl;
        buildx(xqA, lq, xh, xl);
#pragma unroll
        for (int nn = 0; nn < 2; ++nn) {
            f32x4 a;
#pragma unroll
            for (int q = 0; q < 4; ++q) a[q] = bs0[nn];
            a = MFMA(xl, wxh[nn], a);
            a = MFMA(xh, wxl[nn], a);
            a = MFMA(xh, wxh[nn], a);
            const int col = (2 * w + nn) * 16 + lc;
#pragma unroll
            for (int q = 0; q < 4; ++q) sG1[(lq * 4 + q) * 260 + col] = a[q];
        }
    }
    __syncthreads();
    // EW1 prime -> h1(0)
#pragma unroll
    for (int u = 0; u < 2; ++u) {
        const int k = j + u * 32;
        float iv = sG1[m * 260 + k];
        float fv = sG1[m * 260 + 64 + k];
        float gv = sG1[m * 260 + 128 + k];
        float ov = sG1[m * 260 + 192 + k];
        float cn = sigm(fv) * c1[u] + sigm(iv) * tanhr(gv);
        c1[u] = cn;
        float hv = sigm(ov) * tanhr(cn);
        bf16_t h  = (bf16_t)hv;
        bf16_t lo = (bf16_t)(hv - (float)h);
        ((bf16_t*)h1hi)[u * 512 + eoff] = h;
        ((bf16_t*)h1lo)[u * 512 + eoff] = lo;
    }
    __syncthreads();

    // ---------------- main loop: phase A = GEMM2(t) + GEMM1(t+1); phase B = EW both ----------------
    for (int t = 0; t < TT; ++t) {
        const int tnext = (t + 2 < TT) ? t + 2 : TT - 1;
        float4 xq_new = xg[xrow + tnext];

        // h1(t) frags (shared by GEMM2 part-a and GEMM1), h2(t-1) frags
        bf16x8 ah[2], al[2], ph[2], pl[2];
#pragma unroll
        for (int kt = 0; kt < 2; ++kt) {
            ah[kt] = *(const bf16x8*)((const bf16_t*)h1hi + kt * 512 + chunk * 8);
            al[kt] = *(const bf16x8*)((const bf16_t*)h1lo + kt * 512 + chunk * 8);
            ph[kt] = *(const bf16x8*)((const bf16_t*)h2hi + kt * 512 + chunk * 8);
            pl[kt] = *(const bf16x8*)((const bf16_t*)h2lo + kt * 512 + chunk * 8);
        }

        // GEMM2(t): gates2 = bias1 + h1(t) @ w_ih1^T + h2(t-1) @ w_hh1^T
#pragma unroll
        for (int nn = 0; nn < 2; ++nn) {
            f32x4 a;
#pragma unroll
            for (int q = 0; q < 4; ++q) a[q] = bs1[nn];
#pragma unroll
            for (int kt = 0; kt < 2; ++kt) {
                a = MFMA(al[kt], w1h[nn][kt], a);
                a = MFMA(ah[kt], w1l[nn][kt], a);
                a = MFMA(ah[kt], w1h[nn][kt], a);
                a = MFMA(pl[kt], w2h[nn][kt], a);
                a = MFMA(ph[kt], w2l[nn][kt], a);
                a = MFMA(ph[kt], w2h[nn][kt], a);
            }
            const int col = (2 * w + nn) * 16 + lc;
#pragma unroll
            for (int q = 0; q < 4; ++q) sG2[(lq * 4 + q) * 260 + col] = a[q];
        }

        // GEMM1(t+1): gates1 = bias0 + x(t+1) @ w_ih0^T + h1(t) @ w_hh0^T
        if (t + 1 < TT) {
            bf16x8 xh, xl;
            buildx(xq, lq, xh, xl);
#pragma unroll
            for (int nn = 0; nn < 2; ++nn) {
                f32x4 a;
#pragma unroll
                for (int q = 0; q < 4; ++q) a[q] = bs0[nn];
                a = MFMA(xl, wxh[nn], a);
                a = MFMA(xh, wxl[nn], a);
                a = MFMA(xh, wxh[nn], a);
#pragma unroll
                for (int kt = 0; kt < 2; ++kt) {
                    a = MFMA(al[kt], w0h[nn][kt], a);
                    a = MFMA(ah[kt], w0l[nn][kt], a);
                    a = MFMA(ah[kt], w0h[nn][kt], a);
                }
                const int col = (2 * w + nn) * 16 + lc;
#pragma unroll
                for (int q = 0; q < 4; ++q) sG1[(lq * 4 + q) * 260 + col] = a[q];
            }
        }
        __syncthreads();

        // ---------------- phase B: EW2(t) then EW1(t+1) ----------------
#pragma unroll
        for (int u = 0; u < 2; ++u) {
            const int k = j + u * 32;
            float iv = sG2[m * 260 + k];
            float fv = sG2[m * 260 + 64 + k];
            float gv = sG2[m * 260 + 128 + k];
            float ov = sG2[m * 260 + 192 + k];
            float cn = sigm(fv) * c2[u] + sigm(iv) * tanhr(gv);
            c2[u] = cn;
            float hv = sigm(ov) * tanhr(cn);
            bf16_t h  = (bf16_t)hv;
            bf16_t lo = (bf16_t)(hv - (float)h);
            ((bf16_t*)h2hi)[u * 512 + eoff] = h;
            ((bf16_t*)h2lo)[u * 512 + eoff] = lo;
            if (t == TT - 1) sH[m * 68 + k] = hv;
        }
        if (t + 1 < TT) {
#pragma unroll
            for (int u = 0; u < 2; ++u) {
                const int k = j + u * 32;
                float iv = sG1[m * 260 + k];
                float fv = sG1[m * 260 + 64 + k];
                float gv = sG1[m * 260 + 128 + k];
                float ov = sG1[m * 260 + 192 + k];
                float cn = sigm(fv) * c1[u] + sigm(iv) * tanhr(gv);
                c1[u] = cn;
                float hv = sigm(ov) * tanhr(cn);
                bf16_t h  = (bf16_t)hv;
                bf16_t lo = (bf16_t)(hv - (float)h);
                ((bf16_t*)h1hi)[u * 512 + eoff] = h;
                ((bf16_t*)h1lo)[u * 512 + eoff] = lo;
            }
        }
        xq = xq_new;
        __syncthreads();
    }

    // ---------------- FC head ----------------
    {
        const int r = tid >> 5, mo = tid & 31;
        float s = fc1_b[mo];
#pragma unroll 8
        for (int k = 0; k < 64; ++k) s = fmaf(sH[r * 68 + k], fc1_w[mo * 64 + k], s);
        sY[r * 34 + mo] = fmaxf(s, 0.f);
    }
    __syncthreads();
    if (tid < 32) {
        const int r = tid >> 1, o = tid & 1;
        float s = fc2_b[o];
#pragma unroll 8
        for (int mo = 0; mo < 32; ++mo) s = fmaf(sY[r * 34 + mo], fc2_w[o * 32 + mo], s);
        out[(size_t)(rbase + r) * 2 + o] = fmaxf(s, 0.f);
    }
}

extern "C" void kernel_launch(void* const* d_in, const int* in_sizes, int n_in,
                              void* d_out, int out_size, void* d_ws, size_t ws_size,
                              hipStream_t stream) {
    const float* x     = (const float*)d_in[0];
    const float* w_ih0 = (const float*)d_in[1];
    const float* w_hh0 = (const float*)d_in[2];
    const float* b_ih0 = (const float*)d_in[3];
    const float* b_hh0 = (const float*)d_in[4];
    const float* w_ih1 = (const float*)d_in[5];
    const float* w_hh1 = (const float*)d_in[6];
    const float* b_ih1 = (const float*)d_in[7];
    const float* b_hh1 = (const float*)d_in[8];
    const float* fc1_w = (const float*)d_in[9];
    const float* fc1_b = (const float*)d_in[10];
    const float* fc2_w = (const float*)d_in[11];
    const float* fc2_b = (const float*)d_in[12];
    float* out = (float*)d_out;

    const int nB   = in_sizes[0] / (TT * 4);   // 4096 rows
    const int grid = nB / MM;                  // 256 blocks

    lstm_pipe<<<grid, 512, 0, stream>>>(x, w_ih0, w_hh0, b_ih0, b_hh0,
                                        w_ih1, w_hh1, b_ih1, b_hh1,
                                        fc1_w, fc1_b, fc2_w, fc2_b, out);
}

// Round 4
// 654.062 us; speedup vs baseline: 10.9248x; 1.8539x over previous
//
#include <hip/hip_runtime.h>

#define TT 512
#define MM 16      // batch rows per block

typedef __bf16 bf16_t;
typedef bf16_t bf16x8 __attribute__((ext_vector_type(8)));
typedef float  f32x4  __attribute__((ext_vector_type(4)));

#define MFMA(A, B, C) __builtin_amdgcn_mfma_f32_16x16x32_bf16((A), (B), (C), 0, 0, 0)

// fast rcp: IEEE f32 div lowers to ~10-op div_scale/div_fmas sequence without
// fast-math; v_rcp_f32 is 1 trans op and plenty accurate here.
__device__ __forceinline__ float fr(float x)     { return __builtin_amdgcn_rcpf(x); }
__device__ __forceinline__ float sigm(float x)   { return fr(1.f + __expf(-x)); }
__device__ __forceinline__ float tanhr(float x)  { return 1.f - 2.f * fr(__expf(2.f * x) + 1.f); }

__device__ __forceinline__ void split8(const float* p, bf16x8& hi, bf16x8& lo) {
#pragma unroll
    for (int e = 0; e < 8; ++e) {
        float v = p[e];
        bf16_t h = (bf16_t)v;
        hi[e] = h;
        lo[e] = (bf16_t)(v - (float)h);
    }
}

// x A-fragment: only k = 0..3 (lq==0, e<4) valid, rest zero.
__device__ __forceinline__ void buildx(float4 xq, int lq, bf16x8& xh, bf16x8& xl) {
    float v[4] = {xq.x, xq.y, xq.z, xq.w};
#pragma unroll
    for (int e = 0; e < 8; ++e) {
        float vv = (e < 4 && lq == 0) ? v[e] : 0.f;
        bf16_t h = (bf16_t)vv;
        xh[e] = h;
        xl[e] = (bf16_t)(vv - (float)h);
    }
}

// MFMA 16x16x32 bf16 layouts (verified R2/R3):
//   A[m][k]: lane l holds m = l%16, k = (l/16)*8 + e
//   B[k][n]: lane l holds n = l%16, k = (l/16)*8 + e
//   D[m][n]: lane l holds n = l%16, m = (l/16)*4 + q
// h-frag plane (per precision, per layer): bf16 addr = kt*512 + chunk*8 + e,
// read side: chunk = l ^ (l>>4); write side for h(m,k): lp = m + 16*((k&31)>>3),
// chunk = lp ^ ((k&31)>>3)  — identical pair to R3 (algebraically verified).
//
// Wave roles (gate-across-tiles): wave w = 0..3 -> layer 2, h-tile w (h-indices
// w*16+lc); wave 4..7 -> layer 1, h-tile w-4. Each wave computes 4 gate n-tiles
// (cols g*64 + ht*16 + lc, g=0..3) so after MFMA every lane holds i,f,g,o for
// its 4 cells -> elementwise entirely in registers, no gate LDS round-trip.

__global__ __launch_bounds__(512, 2) void lstm_inlane(
    const float* __restrict__ x,
    const float* __restrict__ w_ih0, const float* __restrict__ w_hh0,
    const float* __restrict__ b_ih0, const float* __restrict__ b_hh0,
    const float* __restrict__ w_ih1, const float* __restrict__ w_hh1,
    const float* __restrict__ b_ih1, const float* __restrict__ b_hh1,
    const float* __restrict__ fc1_w, const float* __restrict__ fc1_b,
    const float* __restrict__ fc2_w, const float* __restrict__ fc2_b,
    float* __restrict__ out)
{
    // hpl[buf][plane][...] planes: 0=h1hi 1=h1lo 2=h2hi 3=h2lo
    __shared__ __align__(16) unsigned hpl[2][4][512];
    __shared__ __align__(16) float sH[MM * 68];
    __shared__ float sY[MM * 34];

    const int tid = threadIdx.x;
    const int l   = tid & 63;
    const int wv  = tid >> 6;          // 0..7
    const int rbase = blockIdx.x * MM;

    const int lc = l & 15;
    const int lq = l >> 4;
    const int chunk = l ^ lq;          // frag-read chunk

    const bool isL1 = (wv >= 4);
    const int  ht   = wv & 3;          // h-tile of this wave
    const int  hidx = ht * 16 + lc;    // h-index owned by this lane (0..63)

    // write-side addressing for h(m = lq*4+q, hidx)
    const int ktw = hidx >> 5;
    const int kk  = hidx & 31;
    const int ew  = kk & 7;
    const int kb  = kk >> 3;           // 0..3

    // ---------------- prologue: B-fragments -> registers ----------------
    // L2 waves: w1 (w_ih1) + w2 (w_hh1); L1 waves: w0 (w_hh0) + wx (w_ih0)
    bf16x8 wAh[4][2], wAl[4][2];       // L2: w1 | L1: w0
    bf16x8 wBh[4][2], wBl[4][2];       // L2: w2 | L1: unused (kept zero)
    bf16x8 wxh[4], wxl[4];             // L1 only
    float bs[4];
#pragma unroll
    for (int g = 0; g < 4; ++g) {
        const int ga = g * 64 + hidx;  // absolute gate column
        if (isL1) {
#pragma unroll
            for (int kt = 0; kt < 2; ++kt) {
                const int ko = kt * 32 + lq * 8;
                split8(w_hh0 + ga * 64 + ko, wAh[g][kt], wAl[g][kt]);
                wBh[g][kt] = (bf16x8)(bf16_t)0.f; wBl[g][kt] = (bf16x8)(bf16_t)0.f;
            }
            float4 w4 = *(const float4*)(w_ih0 + ga * 4);
            buildx(w4, lq, wxh[g], wxl[g]);
            bs[g] = b_ih0[ga] + b_hh0[ga];
        } else {
#pragma unroll
            for (int kt = 0; kt < 2; ++kt) {
                const int ko = kt * 32 + lq * 8;
                split8(w_ih1 + ga * 64 + ko, wAh[g][kt], wAl[g][kt]);
                split8(w_hh1 + ga * 64 + ko, wBh[g][kt], wBl[g][kt]);
            }
            bs[g] = b_ih1[ga] + b_hh1[ga];
        }
    }

    // zero all h planes (only h2[0] strictly needed, cheap to do all)
    for (int i = tid; i < 2 * 4 * 512; i += 512) ((unsigned*)hpl)[i] = 0;

    float c_st[4] = {0.f, 0.f, 0.f, 0.f};   // cell state for this lane's 4 cells

    // x: L1 waves load row rbase+lc, time t  (x is [B][T][4] -> float4 idx row*TT+t)
    const float4* xg = (const float4*)x;
    const size_t xrow = (size_t)(rbase + lc) * TT;
    float4 xq0 = make_float4(0, 0, 0, 0), xq = make_float4(0, 0, 0, 0);
    if (isL1) { xq0 = xg[xrow + 0]; xq = xg[xrow + 1]; }

    __syncthreads();

    // ---------------- prime: h1(0) from x(0) only (h1(-1)=0) ----------------
    if (isL1) {
        bf16x8 xh, xl;
        buildx(xq0, lq, xh, xl);
        f32x4 a[4];
#pragma unroll
        for (int g = 0; g < 4; ++g) {
#pragma unroll
            for (int q = 0; q < 4; ++q) a[g][q] = bs[g];
            a[g] = MFMA(xl, wxh[g], a[g]);
            a[g] = MFMA(xh, wxl[g], a[g]);
            a[g] = MFMA(xh, wxh[g], a[g]);
        }
        bf16_t* dhi = (bf16_t*)hpl[0][0];
        bf16_t* dlo = (bf16_t*)hpl[0][1];
#pragma unroll
        for (int q = 0; q < 4; ++q) {
            float cn = sigm(a[1][q]) * c_st[q] + sigm(a[0][q]) * tanhr(a[2][q]);
            c_st[q] = cn;
            float hv = sigm(a[3][q]) * tanhr(cn);
            const int lp = (lq * 4 + q) + 16 * kb;
            const int ad = ktw * 512 + (lp ^ kb) * 8 + ew;
            bf16_t h  = (bf16_t)hv;
            dhi[ad] = h;
            dlo[ad] = (bf16_t)(hv - (float)h);
        }
    }
    __syncthreads();

    // ---------------- main loop: 1 barrier/step ----------------
    // loop t: L2 waves: gates2(t) from h1(t)[cur] + h2(t-1)[cur] -> h2(t)[cur^1]
    //         L1 waves: gates1(t+1) from x(t+1) + h1(t)[cur]     -> h1(t+1)[cur^1]
    int cur = 0;
    for (int t = 0; t < TT; ++t) {
        if (isL1) {
            if (t + 1 < TT) {
                const int tnext = (t + 2 < TT) ? t + 2 : TT - 1;
                float4 xq_new = xg[xrow + tnext];

                bf16x8 ah[2], al[2];
                const bf16_t* p1h = (const bf16_t*)hpl[cur][0];
                const bf16_t* p1l = (const bf16_t*)hpl[cur][1];
#pragma unroll
                for (int kt = 0; kt < 2; ++kt) {
                    ah[kt] = *(const bf16x8*)(p1h + kt * 512 + chunk * 8);
                    al[kt] = *(const bf16x8*)(p1l + kt * 512 + chunk * 8);
                }
                bf16x8 xh, xl;
                buildx(xq, lq, xh, xl);
                f32x4 a[4];
#pragma unroll
                for (int g = 0; g < 4; ++g) {
#pragma unroll
                    for (int q = 0; q < 4; ++q) a[g][q] = bs[g];
                    a[g] = MFMA(xl, wxh[g], a[g]);
                    a[g] = MFMA(xh, wxl[g], a[g]);
                    a[g] = MFMA(xh, wxh[g], a[g]);
#pragma unroll
                    for (int kt = 0; kt < 2; ++kt) {
                        a[g] = MFMA(al[kt], wAh[g][kt], a[g]);
                        a[g] = MFMA(ah[kt], wAl[g][kt], a[g]);
                        a[g] = MFMA(ah[kt], wAh[g][kt], a[g]);
                    }
                }
                bf16_t* dhi = (bf16_t*)hpl[cur ^ 1][0];
                bf16_t* dlo = (bf16_t*)hpl[cur ^ 1][1];
#pragma unroll
                for (int q = 0; q < 4; ++q) {
                    float cn = sigm(a[1][q]) * c_st[q] + sigm(a[0][q]) * tanhr(a[2][q]);
                    c_st[q] = cn;
                    float hv = sigm(a[3][q]) * tanhr(cn);
                    const int lp = (lq * 4 + q) + 16 * kb;
                    const int ad = ktw * 512 + (lp ^ kb) * 8 + ew;
                    bf16_t h  = (bf16_t)hv;
                    dhi[ad] = h;
                    dlo[ad] = (bf16_t)(hv - (float)h);
                }
                xq = xq_new;
            }
        } else {
            bf16x8 ah[2], al[2], ph[2], pl[2];
            const bf16_t* p1h = (const bf16_t*)hpl[cur][0];
            const bf16_t* p1l = (const bf16_t*)hpl[cur][1];
            const bf16_t* p2h = (const bf16_t*)hpl[cur][2];
            const bf16_t* p2l = (const bf16_t*)hpl[cur][3];
#pragma unroll
            for (int kt = 0; kt < 2; ++kt) {
                ah[kt] = *(const bf16x8*)(p1h + kt * 512 + chunk * 8);
                al[kt] = *(const bf16x8*)(p1l + kt * 512 + chunk * 8);
                ph[kt] = *(const bf16x8*)(p2h + kt * 512 + chunk * 8);
                pl[kt] = *(const bf16x8*)(p2l + kt * 512 + chunk * 8);
            }
            f32x4 a[4];
#pragma unroll
            for (int g = 0; g < 4; ++g) {
#pragma unroll
                for (int q = 0; q < 4; ++q) a[g][q] = bs[g];
#pragma unroll
                for (int kt = 0; kt < 2; ++kt) {
                    a[g] = MFMA(al[kt], wAh[g][kt], a[g]);
                    a[g] = MFMA(ah[kt], wAl[g][kt], a[g]);
                    a[g] = MFMA(ah[kt], wAh[g][kt], a[g]);
                    a[g] = MFMA(pl[kt], wBh[g][kt], a[g]);
                    a[g] = MFMA(ph[kt], wBl[g][kt], a[g]);
                    a[g] = MFMA(ph[kt], wBh[g][kt], a[g]);
                }
            }
            bf16_t* dhi = (bf16_t*)hpl[cur ^ 1][2];
            bf16_t* dlo = (bf16_t*)hpl[cur ^ 1][3];
#pragma unroll
            for (int q = 0; q < 4; ++q) {
                float cn = sigm(a[1][q]) * c_st[q] + sigm(a[0][q]) * tanhr(a[2][q]);
                c_st[q] = cn;
                float hv = sigm(a[3][q]) * tanhr(cn);
                const int lp = (lq * 4 + q) + 16 * kb;
                const int ad = ktw * 512 + (lp ^ kb) * 8 + ew;
                bf16_t h  = (bf16_t)hv;
                dhi[ad] = h;
                dlo[ad] = (bf16_t)(hv - (float)h);
                if (t == TT - 1) sH[(lq * 4 + q) * 68 + hidx] = hv;
            }
        }
        cur ^= 1;
        __syncthreads();
    }

    // ---------------- FC head ----------------
    {
        const int r = tid >> 5, mo = tid & 31;
        float s = fc1_b[mo];
#pragma unroll 8
        for (int k = 0; k < 64; ++k) s = fmaf(sH[r * 68 + k], fc1_w[mo * 64 + k], s);
        sY[r * 34 + mo] = fmaxf(s, 0.f);
    }
    __syncthreads();
    if (tid < 32) {
        const int r = tid >> 1, o = tid & 1;
        float s = fc2_b[o];
#pragma unroll 8
        for (int mo = 0; mo < 32; ++mo) s = fmaf(sY[r * 34 + mo], fc2_w[o * 32 + mo], s);
        out[(size_t)(rbase + r) * 2 + o] = fmaxf(s, 0.f);
    }
}

extern "C" void kernel_launch(void* const* d_in, const int* in_sizes, int n_in,
                              void* d_out, int out_size, void* d_ws, size_t ws_size,
                              hipStream_t stream) {
    const float* x     = (const float*)d_in[0];
    const float* w_ih0 = (const float*)d_in[1];
    const float* w_hh0 = (const float*)d_in[2];
    const float* b_ih0 = (const float*)d_in[3];
    const float* b_hh0 = (const float*)d_in[4];
    const float* w_ih1 = (const float*)d_in[5];
    const float* w_hh1 = (const float*)d_in[6];
    const float* b_ih1 = (const float*)d_in[7];
    const float* b_hh1 = (const float*)d_in[8];
    const float* fc1_w = (const float*)d_in[9];
    const float* fc1_b = (const float*)d_in[10];
    const float* fc2_w = (const float*)d_in[11];
    const float* fc2_b = (const float*)d_in[12];
    float* out = (float*)d_out;

    const int nB   = in_sizes[0] / (TT * 4);   // 4096 rows
    const int grid = nB / MM;                  // 256 blocks

    lstm_inlane<<<grid, 512, 0, stream>>>(x, w_ih0, w_hh0, b_ih0, b_hh0,
                                          w_ih1, w_hh1, b_ih1, b_hh1,
                                          fc1_w, fc1_b, fc2_w, fc2_b, out);
}

// Round 5
// 423.094 us; speedup vs baseline: 16.8887x; 1.5459x over previous
//
#include <hip/hip_runtime.h>

#define TT 512
#define MM 16      // batch rows per block

typedef _Float16 f16_t;
typedef f16_t f16x8 __attribute__((ext_vector_type(8)));
typedef float  f32x4 __attribute__((ext_vector_type(4)));

#define MFMA16(A, B, C) __builtin_amdgcn_mfma_f32_16x16x32_f16((A), (B), (C), 0, 0, 0)

__device__ __forceinline__ float fr(float x) { return __builtin_amdgcn_rcpf(x); }

// LSTM cell update: 5 exp + 4 rcp, NaN-safe.
//  sigma(f)=1/(1+e^-f); sigma(i)*tanh(g)=(C-1)/((1+B)(C+1)), C=e^2g bounded (|g_pre|<~15);
//  tanh(c') via 1-2/(E+1): E=inf -> rcp=0 -> tanh=1 (c' is the only unbounded input).
__device__ __forceinline__ float cellEW(float pi, float pf, float pg, float po, float& c) {
    float A = __expf(-pf);
    float B = __expf(-pi);
    float C = __expf(2.f * pg);
    float ra = fr(1.f + A);
    float rb = fr((1.f + B) * (C + 1.f));
    float cn = fmaf(c, ra, (C - 1.f) * rb);
    c = cn;
    float D = __expf(-po);
    float E = __expf(2.f * cn);
    float rd = fr(1.f + D);
    float re = fr(E + 1.f);
    return rd * fmaf(-2.f, re, 1.f);
}

__device__ __forceinline__ f16x8 cvt8(const float* p) {
    f16x8 r;
#pragma unroll
    for (int e = 0; e < 8; ++e) r[e] = (f16_t)p[e];
    return r;
}

// x A-fragment: only k = 0..3 (lq==0, e<4) valid, rest zero.
__device__ __forceinline__ f16x8 buildxf(float4 xq, int lq) {
    float v[4] = {xq.x, xq.y, xq.z, xq.w};
    f16x8 r;
#pragma unroll
    for (int e = 0; e < 8; ++e) r[e] = (e < 4 && lq == 0) ? (f16_t)v[e] : (f16_t)0.f;
    return r;
}

// MFMA 16x16x32 f16 layouts (same lane maps as bf16, verified R2-R4; dtype-independent):
//   A[m][k]: lane l holds m = l%16, k = (l/16)*8 + e
//   B[k][n]: lane l holds n = l%16, k = (l/16)*8 + e
//   D[m][n]: lane l holds n = l%16, m = (l/16)*4 + q
// h-frag plane (per layer): f16 addr = kt*512 + chunk*8 + e
//   read side: chunk = l ^ (l>>4)
//   write side for h(m,k): lp = m + 16*((k&31)>>3), chunk = lp ^ ((k&31)>>3)
// (identical read/write swizzle pair as R3/R4, algebraically verified there).
//
// Wave roles: waves 0..3 -> layer 2 (h-tile = wv), waves 4..7 -> layer 1 (h-tile = wv-4).
// Each wave computes all 4 gate n-tiles of its h-tile -> whole cell update in registers.

__global__ __launch_bounds__(512, 2) void lstm_f16(
    const float* __restrict__ x,
    const float* __restrict__ w_ih0, const float* __restrict__ w_hh0,
    const float* __restrict__ b_ih0, const float* __restrict__ b_hh0,
    const float* __restrict__ w_ih1, const float* __restrict__ w_hh1,
    const float* __restrict__ b_ih1, const float* __restrict__ b_hh1,
    const float* __restrict__ fc1_w, const float* __restrict__ fc1_b,
    const float* __restrict__ fc2_w, const float* __restrict__ fc2_b,
    float* __restrict__ out)
{
    // hpl[buf][layer][...]: layer 0 = h1, 1 = h2. Plane = 2 ktiles * 64 chunks * 8 f16.
    __shared__ __align__(16) unsigned hpl[2][2][512];
    __shared__ __align__(16) float sH[MM * 68];
    __shared__ float sY[MM * 34];

    const int tid = threadIdx.x;
    const int l   = tid & 63;
    const int wv  = tid >> 6;
    const int rbase = blockIdx.x * MM;

    const int lc = l & 15;
    const int lq = l >> 4;
    const int chunk = l ^ lq;

    const bool isL1 = (wv >= 4);
    const int  ht   = wv & 3;
    const int  hidx = ht * 16 + lc;

    // write-side addressing for h(m = lq*4+q, hidx)
    const int ktw = hidx >> 5;
    const int kk  = hidx & 31;
    const int ew  = kk & 7;
    const int kb  = kk >> 3;

    // ---------------- prologue: B-fragments (single f16) -> registers ----------------
    // L2 waves: wA = w_ih1, wB = w_hh1;  L1 waves: wA = w_hh0, wx = w_ih0.
    f16x8 wA[4][2], wB[4][2], wx[4];
    float bs[4];
#pragma unroll
    for (int g = 0; g < 4; ++g) {
        const int ga = g * 64 + hidx;
        if (isL1) {
#pragma unroll
            for (int kt = 0; kt < 2; ++kt)
                wA[g][kt] = cvt8(w_hh0 + ga * 64 + kt * 32 + lq * 8);
            float4 w4 = *(const float4*)(w_ih0 + ga * 4);
            wx[g] = buildxf(w4, lq);
            bs[g] = b_ih0[ga] + b_hh0[ga];
        } else {
#pragma unroll
            for (int kt = 0; kt < 2; ++kt) {
                wA[g][kt] = cvt8(w_ih1 + ga * 64 + kt * 32 + lq * 8);
                wB[g][kt] = cvt8(w_hh1 + ga * 64 + kt * 32 + lq * 8);
            }
            bs[g] = b_ih1[ga] + b_hh1[ga];
        }
    }

    for (int i = tid; i < 2 * 2 * 512; i += 512) ((unsigned*)hpl)[i] = 0;

    float c_st[4] = {0.f, 0.f, 0.f, 0.f};

    const float4* xg = (const float4*)x;
    const size_t xrow = (size_t)(rbase + lc) * TT;
    float4 xq0 = make_float4(0, 0, 0, 0), xq = make_float4(0, 0, 0, 0);
    if (isL1) { xq0 = xg[xrow + 0]; xq = xg[xrow + 1]; }

    __syncthreads();

    // ---------------- prime: h1(0) from x(0) only ----------------
    if (isL1) {
        f16x8 xf = buildxf(xq0, lq);
        f32x4 a[4];
#pragma unroll
        for (int g = 0; g < 4; ++g) {
#pragma unroll
            for (int q = 0; q < 4; ++q) a[g][q] = bs[g];
            a[g] = MFMA16(xf, wx[g], a[g]);
        }
        f16_t* dst = (f16_t*)hpl[0][0];
#pragma unroll
        for (int q = 0; q < 4; ++q) {
            float hv = cellEW(a[0][q], a[1][q], a[2][q], a[3][q], c_st[q]);
            const int lp = (lq * 4 + q) + 16 * kb;
            dst[ktw * 512 + (lp ^ kb) * 8 + ew] = (f16_t)hv;
        }
    }
    __syncthreads();

    // ---------------- main loop: 1 barrier/step ----------------
    // L2 waves: gates2(t) from h1(t)[cur] + h2(t-1)[cur] -> h2(t)[cur^1]
    // L1 waves: gates1(t+1) from x(t+1) + h1(t)[cur]     -> h1(t+1)[cur^1]
    int cur = 0;
    for (int t = 0; t < TT; ++t) {
        if (isL1) {
            if (t + 1 < TT) {
                const int tnext = (t + 2 < TT) ? t + 2 : TT - 1;
                float4 xq_new = xg[xrow + tnext];

                const f16_t* p1 = (const f16_t*)hpl[cur][0];
                f16x8 ah[2];
#pragma unroll
                for (int kt = 0; kt < 2; ++kt)
                    ah[kt] = *(const f16x8*)(p1 + kt * 512 + chunk * 8);
                f16x8 xf = buildxf(xq, lq);

                f32x4 a[4];
                __builtin_amdgcn_s_setprio(1);
#pragma unroll
                for (int g = 0; g < 4; ++g) {
#pragma unroll
                    for (int q = 0; q < 4; ++q) a[g][q] = bs[g];
                    a[g] = MFMA16(xf, wx[g], a[g]);
                    a[g] = MFMA16(ah[0], wA[g][0], a[g]);
                    a[g] = MFMA16(ah[1], wA[g][1], a[g]);
                }
                __builtin_amdgcn_s_setprio(0);

                f16_t* dst = (f16_t*)hpl[cur ^ 1][0];
#pragma unroll
                for (int q = 0; q < 4; ++q) {
                    float hv = cellEW(a[0][q], a[1][q], a[2][q], a[3][q], c_st[q]);
                    const int lp = (lq * 4 + q) + 16 * kb;
                    dst[ktw * 512 + (lp ^ kb) * 8 + ew] = (f16_t)hv;
                }
                xq = xq_new;
            }
        } else {
            const f16_t* p1 = (const f16_t*)hpl[cur][0];
            const f16_t* p2 = (const f16_t*)hpl[cur][1];
            f16x8 ah[2], ph[2];
#pragma unroll
            for (int kt = 0; kt < 2; ++kt) {
                ah[kt] = *(const f16x8*)(p1 + kt * 512 + chunk * 8);
                ph[kt] = *(const f16x8*)(p2 + kt * 512 + chunk * 8);
            }

            f32x4 a[4];
            __builtin_amdgcn_s_setprio(1);
#pragma unroll
            for (int g = 0; g < 4; ++g) {
#pragma unroll
                for (int q = 0; q < 4; ++q) a[g][q] = bs[g];
                a[g] = MFMA16(ah[0], wA[g][0], a[g]);
                a[g] = MFMA16(ah[1], wA[g][1], a[g]);
                a[g] = MFMA16(ph[0], wB[g][0], a[g]);
                a[g] = MFMA16(ph[1], wB[g][1], a[g]);
            }
            __builtin_amdgcn_s_setprio(0);

            f16_t* dst = (f16_t*)hpl[cur ^ 1][1];
#pragma unroll
            for (int q = 0; q < 4; ++q) {
                float hv = cellEW(a[0][q], a[1][q], a[2][q], a[3][q], c_st[q]);
                const int lp = (lq * 4 + q) + 16 * kb;
                dst[ktw * 512 + (lp ^ kb) * 8 + ew] = (f16_t)hv;
                if (t == TT - 1) sH[(lq * 4 + q) * 68 + hidx] = hv;
            }
        }
        cur ^= 1;
        __syncthreads();
    }

    // ---------------- FC head ----------------
    {
        const int r = tid >> 5, mo = tid & 31;
        float s = fc1_b[mo];
#pragma unroll 8
        for (int k = 0; k < 64; ++k) s = fmaf(sH[r * 68 + k], fc1_w[mo * 64 + k], s);
        sY[r * 34 + mo] = fmaxf(s, 0.f);
    }
    __syncthreads();
    if (tid < 32) {
        const int r = tid >> 1, o = tid & 1;
        float s = fc2_b[o];
#pragma unroll 8
        for (int mo = 0; mo < 32; ++mo) s = fmaf(sY[r * 34 + mo], fc2_w[o * 32 + mo], s);
        out[(size_t)(rbase + r) * 2 + o] = fmaxf(s, 0.f);
    }
}

extern "C" void kernel_launch(void* const* d_in, const int* in_sizes, int n_in,
                              void* d_out, int out_size, void* d_ws, size_t ws_size,
                              hipStream_t stream) {
    const float* x     = (const float*)d_in[0];
    const float* w_ih0 = (const float*)d_in[1];
    const float* w_hh0 = (const float*)d_in[2];
    const float* b_ih0 = (const float*)d_in[3];
    const float* b_hh0 = (const float*)d_in[4];
    const float* w_ih1 = (const float*)d_in[5];
    const float* w_hh1 = (const float*)d_in[6];
    const float* b_ih1 = (const float*)d_in[7];
    const float* b_hh1 = (const float*)d_in[8];
    const float* fc1_w = (const float*)d_in[9];
    const float* fc1_b = (const float*)d_in[10];
    const float* fc2_w = (const float*)d_in[11];
    const float* fc2_b = (const float*)d_in[12];
    float* out = (float*)d_out;

    const int nB   = in_sizes[0] / (TT * 4);   // 4096 rows
    const int grid = nB / MM;                  // 256 blocks

    lstm_f16<<<grid, 512, 0, stream>>>(x, w_ih0, w_hh0, b_ih0, b_hh0,
                                       w_ih1, w_hh1, b_ih1, b_hh1,
                                       fc1_w, fc1_b, fc2_w, fc2_b, out);
}